// Round 1
// baseline (2394.951 us; speedup 1.0000x reference)
//
#include <hip/hip_runtime.h>

// Problem constants
#define BB 32
#define CC 256
#define OO 256
#define KS 7
#define HH 31
#define WW 31
#define HO 25
#define WO 25
#define PP 625      // HO*WO
#define SS 49       // KS*KS

// Tiling
#define TO 64       // o tile
#define TP 128      // p tile
#define BKC 16      // c chunk
#define XROWS 12    // x slab rows staged per c
#define XLEN (XROWS*WW)   // 372 floats per c

// ---------------------------------------------------------------------------
// Pre-pass: transpose weight [O][C][S] -> Wt[S][C][O] so that the main
// kernel's modulated-weight tile fill reads contiguous-in-o (float4 coalesced).
// ---------------------------------------------------------------------------
__global__ __launch_bounds__(OO) void transpose_w(const float* __restrict__ w,
                                                  float* __restrict__ wt) {
    const int c = blockIdx.x;      // 0..255
    const int o = threadIdx.x;     // 0..255
    const float* src = w + ((size_t)o * CC + c) * SS;
    // each thread walks its own contiguous 196B -> full L1 line reuse; writes
    // are coalesced across lanes (consecutive o).
#pragma unroll
    for (int s = 0; s < SS; ++s) {
        wt[((size_t)s * CC + c) * OO + o] = src[s];
    }
}

// ---------------------------------------------------------------------------
// Main kernel: per-batch implicit-GEMM.
//   out[b][o][p] = sum_{c,s} x[b][c][h(p)+kk][w(p)+ll] * kern[b][c][s] * W[o][c][s]
// Block: 256 threads, computes TO x TP output tile for one b.
// K-loop: c-chunks of BKC outer (x slab staged once), 49 shifts inner
// (modulated weight tile refilled per shift, kern folded in).
// ---------------------------------------------------------------------------
__global__ __launch_bounds__(256) void dwconv_main(
        const float* __restrict__ x, const float* __restrict__ kern,
        const float* __restrict__ wt, const float* __restrict__ bias,
        float* __restrict__ out) {
    __shared__ float Xs[BKC * XLEN];   // 23808 B
    __shared__ float Ws[BKC * TO];     // 4096 B

    const int tid = threadIdx.x;
    const int bx = blockIdx.x;     // p tile 0..4
    const int oy = blockIdx.y;     // o tile 0..3
    const int b  = blockIdx.z;     // batch

    const int p0 = bx * TP;
    const int row0 = p0 / HO;      // first x row needed
    const int o0 = oy * TO;

    const int tp = tid & 31;       // p lane group
    const int to = tid >> 5;       // o group 0..7

    // Per-thread x-slab offsets for its 4 p's (p = p0 + tp + 32*j).
    int off[4];
#pragma unroll
    for (int j = 0; j < 4; ++j) {
        int p = p0 + tp + 32 * j;
        int pc = p < PP ? p : PP - 1;   // clamp (tile 4 tail) - results discarded
        int h = pc / HO;
        int w = pc - h * HO;
        off[j] = (h - row0) * WW + w;
    }

    float acc[8][4];
#pragma unroll
    for (int oi = 0; oi < 8; ++oi)
#pragma unroll
        for (int j = 0; j < 4; ++j) acc[oi][j] = 0.f;

    const int xlen = (HH * WW - row0 * WW) < XLEN ? (HH * WW - row0 * WW) : XLEN;
    const float* xbase = x + (size_t)b * CC * (HH * WW) + row0 * WW;

    for (int c0 = 0; c0 < CC; c0 += BKC) {
        __syncthreads();   // previous chunk's compute done before restaging Xs
        // ---- stage x slab: BKC channels x xlen floats, coalesced ----
        for (int ci = 0; ci < BKC; ++ci) {
            const float* src = xbase + (size_t)(c0 + ci) * (HH * WW);
            for (int t = tid; t < xlen; t += 256)
                Xs[ci * XLEN + t] = src[t];
        }
        for (int s = 0; s < SS; ++s) {
            __syncthreads();  // Xs ready (s==0) / previous Ws fully consumed
            // ---- fill modulated weight tile: Ws[ci][oj] = Wt[s][c][o]*kern[b][c][s]
            {
                const int ci  = tid >> 4;            // tid/16: 0..15
                const int ojq = (tid & 15) * 4;      // o quad within tile
                const float km = kern[((size_t)b * CC + c0 + ci) * SS + s];
                const float4 wv = *(const float4*)(wt + ((size_t)s * CC + c0 + ci) * OO + o0 + ojq);
                float4 m;
                m.x = wv.x * km; m.y = wv.y * km; m.z = wv.z * km; m.w = wv.w * km;
                *(float4*)(Ws + ci * TO + ojq) = m;
            }
            __syncthreads();
            const int kk = s / KS;
            const int ll = s - kk * KS;
            const float* xr = Xs + kk * WW + ll;
#pragma unroll
            for (int ci = 0; ci < BKC; ++ci) {
                const float a0 = xr[ci * XLEN + off[0]];
                const float a1 = xr[ci * XLEN + off[1]];
                const float a2 = xr[ci * XLEN + off[2]];
                const float a3 = xr[ci * XLEN + off[3]];
                const float* wrow = Ws + ci * TO + to * 8;
#pragma unroll
                for (int oi = 0; oi < 8; ++oi) {
                    const float wv = wrow[oi];
                    acc[oi][0] += wv * a0;
                    acc[oi][1] += wv * a1;
                    acc[oi][2] += wv * a2;
                    acc[oi][3] += wv * a3;
                }
            }
        }
    }

    // ---- epilogue: add bias, store (lane-consecutive p -> coalesced) ----
#pragma unroll
    for (int oi = 0; oi < 8; ++oi) {
        const int o = o0 + to * 8 + oi;
        const float bv = bias[o];
        float* orow = out + ((size_t)b * OO + o) * PP;
#pragma unroll
        for (int j = 0; j < 4; ++j) {
            const int p = p0 + tp + 32 * j;
            if (p < PP) orow[p] = acc[oi][j] + bv;
        }
    }
}

// ---------------------------------------------------------------------------
// Fallback (only if ws too small for the weight transpose): naive but correct.
// ---------------------------------------------------------------------------
__global__ __launch_bounds__(256) void dwconv_naive(
        const float* __restrict__ x, const float* __restrict__ kern,
        const float* __restrict__ w, const float* __restrict__ bias,
        float* __restrict__ out) {
    const int idx = blockIdx.x * 256 + threadIdx.x;
    if (idx >= BB * OO * PP) return;
    const int p = idx % PP;
    const int o = (idx / PP) % OO;
    const int b = idx / (PP * OO);
    const int h = p / HO;
    const int wq = p - h * HO;
    float acc = 0.f;
    for (int c = 0; c < CC; ++c) {
        const float* xp = x + ((size_t)(b * CC + c)) * (HH * WW) + h * WW + wq;
        const float* kp = kern + ((size_t)b * CC + c) * SS;
        const float* wp = w + ((size_t)o * CC + c) * SS;
#pragma unroll
        for (int s = 0; s < SS; ++s) {
            const int kk = s / KS;
            const int ll = s - kk * KS;
            acc += xp[kk * WW + ll] * kp[s] * wp[s];
        }
    }
    out[idx] = acc + bias[o];
}

extern "C" void kernel_launch(void* const* d_in, const int* in_sizes, int n_in,
                              void* d_out, int out_size, void* d_ws, size_t ws_size,
                              hipStream_t stream) {
    const float* x    = (const float*)d_in[0];
    const float* kern = (const float*)d_in[1];
    const float* w    = (const float*)d_in[2];
    const float* bias = (const float*)d_in[3];
    float* out = (float*)d_out;

    const size_t wt_bytes = (size_t)SS * CC * OO * sizeof(float);  // 12.85 MB
    if (ws_size >= wt_bytes) {
        float* wtp = (float*)d_ws;
        transpose_w<<<dim3(CC), dim3(OO), 0, stream>>>(w, wtp);
        dim3 grid(5, 4, BB);   // p tiles, o tiles, batch
        dwconv_main<<<grid, dim3(256), 0, stream>>>(x, kern, wtp, bias, out);
    } else {
        const int total = BB * OO * PP;
        dwconv_naive<<<dim3((total + 255) / 256), dim3(256), 0, stream>>>(
            x, kern, w, bias, out);
    }
}

// Round 3
// 389.540 us; speedup vs baseline: 6.1482x; 6.1482x over previous
//
#include <hip/hip_runtime.h>
#include <hip/hip_bf16.h>

typedef __attribute__((ext_vector_type(8))) short short8;
typedef __attribute__((ext_vector_type(4))) float floatx4;

#define BB 32
#define CC 256
#define OO 256
#define KS 7
#define HH 31
#define WW 31
#define HO 25
#define PP 625
#define SS 49

#define SLAB_PITCH 40        // ushort elems per row: 32 ci + 8 pad = 80 B
#define SLAB_ROWS  372       // 12 rows x 31 cols

// ws layout: Wt4 bf16 [49][8][256][32]  (6,422,528 B)  then kernf f32 [32][49][256]
#define WT4_ELEMS  ((size_t)SS * 8 * CC * 32)
#define WT4_BYTES  (WT4_ELEMS * 2)
#define KERNF_BYTES ((size_t)BB * SS * CC * 4)

static __device__ __forceinline__ unsigned pk2(float lo, float hi) {
    float2 f; f.x = lo; f.y = hi;
    __hip_bfloat162 h = __float22bfloat162_rn(f);   // v_cvt_pk_bf16_f32 on gfx950
    unsigned r;
    __builtin_memcpy(&r, &h, sizeof(r));            // bit_cast rejected (non-trivially-copyable)
    return r;
}
static __device__ __forceinline__ float bflo(unsigned u) {
    return __builtin_bit_cast(float, u << 16);
}
static __device__ __forceinline__ float bfhi(unsigned u) {
    return __builtin_bit_cast(float, u & 0xffff0000u);
}

// Build modulated A-fragment: 8 bf16 = bf16( wt[j] * kern[j] ), j = quad*8..+7
static __device__ __forceinline__ short8 modpack(uint4 wv, float4 k0, float4 k1) {
    float p0 = bflo(wv.x) * k0.x, p1 = bfhi(wv.x) * k0.y;
    float p2 = bflo(wv.y) * k0.z, p3 = bfhi(wv.y) * k0.w;
    float p4 = bflo(wv.z) * k1.x, p5 = bfhi(wv.z) * k1.y;
    float p6 = bflo(wv.w) * k1.z, p7 = bfhi(wv.w) * k1.w;
    uint4 r;
    r.x = pk2(p0, p1); r.y = pk2(p2, p3); r.z = pk2(p4, p5); r.w = pk2(p6, p7);
    return __builtin_bit_cast(short8, r);
}

// ---------------------------------------------------------------------------
// Prepass (merged): blocks 0..255 repack weight -> Wt4[s][cb][o][ci] bf16;
// blocks 256..287 reorder kern -> kernf[b][s][c] f32.
// ---------------------------------------------------------------------------
__global__ __launch_bounds__(256) void prepack(
        const float* __restrict__ w, const float* __restrict__ kern,
        unsigned short* __restrict__ wt4, float* __restrict__ kernf) {
    __shared__ float lbuf[CC * SS];   // 50176 B
    const int tid = threadIdx.x;
    const int bid = blockIdx.x;
    if (bid < OO) {
        const int o = bid;
        const float* src = w + (size_t)o * CC * SS;
        for (int i = tid; i < CC * SS; i += 256) lbuf[i] = src[i];
        __syncthreads();
        for (int it = 0; it < 7; ++it) {
            int idx = tid + it * 256;
            if (idx < SS * 32) {                       // 1568 16B-chunks
                int coct = idx & 3, cbv = (idx >> 2) & 7, s = idx >> 5;
                int cbase = cbv * 32 + coct * 8;
                float v[8];
#pragma unroll
                for (int j = 0; j < 8; ++j) v[j] = lbuf[(cbase + j) * SS + s];
                uint4 pkt;
                pkt.x = pk2(v[0], v[1]); pkt.y = pk2(v[2], v[3]);
                pkt.z = pk2(v[4], v[5]); pkt.w = pk2(v[6], v[7]);
                *(uint4*)(wt4 + (((size_t)(s * 8 + cbv) * CC + o) * 32 + coct * 8)) = pkt;
            }
        }
    } else {
        const int b = bid - OO;
        const float* src = kern + (size_t)b * CC * SS;
        for (int i = tid; i < CC * SS; i += 256) lbuf[i] = src[i];
        __syncthreads();
        for (int it = 0; it < SS; ++it) {              // 49*256 == 12544 exact
            int idx = tid + it * 256;
            int s = idx >> 8, c = idx & 255;
            kernf[((size_t)b * SS + s) * CC + c] = lbuf[c * SS + s];
        }
    }
}

// ---------------------------------------------------------------------------
// Main: block = 64o x 128p tile of one batch. 4 waves of 32o x 64p.
// K-loop: cb (8 chunks of 32 c) outer staging slabT[pos][ci] bf16 in LDS;
// s = kk*7+ll inner, A-frags modulated in registers from Wt4/kernf (global),
// B-frags ds_read_b128 from slab at immediate shift offsets. No per-s barrier.
// ---------------------------------------------------------------------------
__global__ __launch_bounds__(256) void dwconv_mfma(
        const float* __restrict__ x,
        const unsigned short* __restrict__ wt4, const float* __restrict__ kernf,
        const float* __restrict__ bias, float* __restrict__ out) {
    __shared__ unsigned short slab[SLAB_ROWS * SLAB_PITCH];   // 29760 B

    const int tid = threadIdx.x;
    const int px = blockIdx.x, oy = blockIdx.y, b = blockIdx.z;
    const int p0 = px * 128, o0 = oy * 64;
    const int h0 = p0 / HO;
    const int rows = (HH - h0) < 12 ? (HH - h0) : 12;
    const int npos = rows * WW;

    const int lane = tid & 63, wid = tid >> 6;
    const int ow = wid & 1, pw = wid >> 1;        // o-sub(32), p-sub(64)
    const int lo16 = lane & 15, quad = lane >> 4; // quad = k-group for frags

    // B-fragment per-lane row offsets (ushort elems) for 4 p-subtiles of 16
    int bOffB[4];
#pragma unroll
    for (int pt = 0; pt < 4; ++pt) {
        int p = p0 + pw * 64 + pt * 16 + lo16;
        if (p > PP - 1) p = PP - 1;               // clamp; store guarded later
        int h = p / HO, ww_ = p - h * HO;
        int pos = (h - h0) * WW + ww_;
        bOffB[pt] = pos * SLAB_PITCH + quad * 8;
    }
    const int oA0 = o0 + ow * 32 + lo16;          // A m-rows for 2 o-subtiles
    const int oA1 = oA0 + 16;

    floatx4 acc[2][4];
#pragma unroll
    for (int at = 0; at < 2; ++at)
#pragma unroll
        for (int pt = 0; pt < 4; ++pt)
            acc[at][pt] = (floatx4){0.f, 0.f, 0.f, 0.f};

    for (int cb = 0; cb < 8; ++cb) {
        __syncthreads();
        // ---- stage slabT[pos][ci] : coalesced x reads, b128 LDS writes ----
        {
            const int coct = tid >> 6;            // 4 octs of 8 ci
            const int lpos = tid & 63;
            const float* xsrc = x + ((size_t)(b * CC + cb * 32 + coct * 8)) * (HH * WW)
                                  + h0 * WW;
#pragma unroll
            for (int it = 0; it < 6; ++it) {
                int pos = lpos + it * 64;
                if (pos < npos) {
                    float v[8];
#pragma unroll
                    for (int j = 0; j < 8; ++j) v[j] = xsrc[j * (HH * WW) + pos];
                    uint4 pkt;
                    pkt.x = pk2(v[0], v[1]); pkt.y = pk2(v[2], v[3]);
                    pkt.z = pk2(v[4], v[5]); pkt.w = pk2(v[6], v[7]);
                    *(uint4*)(slab + pos * SLAB_PITCH + coct * 8) = pkt;
                }
            }
        }
        __syncthreads();

        // global elem offsets at s=0 for this cb
        size_t wtOff0 = ((size_t)cb * CC + oA0) * 32 + quad * 8;
        size_t wtOff1 = ((size_t)cb * CC + oA1) * 32 + quad * 8;
        size_t kfOff  = (size_t)b * SS * CC + cb * 32 + quad * 8;

        for (int kk = 0; kk < KS; ++kk) {
            const unsigned short* slabK = slab + kk * WW * SLAB_PITCH;
#pragma unroll
            for (int ll = 0; ll < KS; ++ll) {
                uint4 wa0 = *(const uint4*)(wt4 + wtOff0);
                uint4 wa1 = *(const uint4*)(wt4 + wtOff1);
                float4 kq0 = *(const float4*)(kernf + kfOff);
                float4 kq1 = *(const float4*)(kernf + kfOff + 4);
                short8 sa0 = modpack(wa0, kq0, kq1);
                short8 sa1 = modpack(wa1, kq0, kq1);

                short8 sb0 = *(const short8*)(slabK + ll * SLAB_PITCH + bOffB[0]);
                short8 sb1 = *(const short8*)(slabK + ll * SLAB_PITCH + bOffB[1]);
                short8 sb2 = *(const short8*)(slabK + ll * SLAB_PITCH + bOffB[2]);
                short8 sb3 = *(const short8*)(slabK + ll * SLAB_PITCH + bOffB[3]);

                acc[0][0] = __builtin_amdgcn_mfma_f32_16x16x32_bf16(sa0, sb0, acc[0][0], 0, 0, 0);
                acc[0][1] = __builtin_amdgcn_mfma_f32_16x16x32_bf16(sa0, sb1, acc[0][1], 0, 0, 0);
                acc[0][2] = __builtin_amdgcn_mfma_f32_16x16x32_bf16(sa0, sb2, acc[0][2], 0, 0, 0);
                acc[0][3] = __builtin_amdgcn_mfma_f32_16x16x32_bf16(sa0, sb3, acc[0][3], 0, 0, 0);
                acc[1][0] = __builtin_amdgcn_mfma_f32_16x16x32_bf16(sa1, sb0, acc[1][0], 0, 0, 0);
                acc[1][1] = __builtin_amdgcn_mfma_f32_16x16x32_bf16(sa1, sb1, acc[1][1], 0, 0, 0);
                acc[1][2] = __builtin_amdgcn_mfma_f32_16x16x32_bf16(sa1, sb2, acc[1][2], 0, 0, 0);
                acc[1][3] = __builtin_amdgcn_mfma_f32_16x16x32_bf16(sa1, sb3, acc[1][3], 0, 0, 0);

                wtOff0 += (size_t)8 * CC * 32;   // next s
                wtOff1 += (size_t)8 * CC * 32;
                kfOff  += CC;
            }
        }
    }

    // ---- epilogue: D col = p (lane&15), row = o (quad*4 + reg) ----
    const int pbase = p0 + pw * 64;
#pragma unroll
    for (int at = 0; at < 2; ++at) {
#pragma unroll
        for (int pt = 0; pt < 4; ++pt) {
            int p = pbase + pt * 16 + lo16;
            if (p < PP) {
#pragma unroll
                for (int r = 0; r < 4; ++r) {
                    int o = o0 + ow * 32 + at * 16 + quad * 4 + r;
                    out[((size_t)(b * OO + o)) * PP + p] = acc[at][pt][r] + bias[o];
                }
            }
        }
    }
}

// ---------------------------------------------------------------------------
// Fallback if ws too small: naive but correct.
// ---------------------------------------------------------------------------
__global__ __launch_bounds__(256) void dwconv_naive(
        const float* __restrict__ x, const float* __restrict__ kern,
        const float* __restrict__ w, const float* __restrict__ bias,
        float* __restrict__ out) {
    const int idx = blockIdx.x * 256 + threadIdx.x;
    if (idx >= BB * OO * PP) return;
    const int p = idx % PP;
    const int o = (idx / PP) % OO;
    const int b = idx / (PP * OO);
    const int h = p / HO;
    const int wq = p - h * HO;
    float acc = 0.f;
    for (int c = 0; c < CC; ++c) {
        const float* xp = x + ((size_t)(b * CC + c)) * (HH * WW) + h * WW + wq;
        const float* kp = kern + ((size_t)b * CC + c) * SS;
        const float* wp = w + ((size_t)o * CC + c) * SS;
#pragma unroll
        for (int s = 0; s < SS; ++s) {
            const int kk = s / KS;
            const int ll = s - kk * KS;
            acc += xp[kk * WW + ll] * kp[s] * wp[s];
        }
    }
    out[idx] = acc + bias[o];
}

extern "C" void kernel_launch(void* const* d_in, const int* in_sizes, int n_in,
                              void* d_out, int out_size, void* d_ws, size_t ws_size,
                              hipStream_t stream) {
    const float* x    = (const float*)d_in[0];
    const float* kern = (const float*)d_in[1];
    const float* w    = (const float*)d_in[2];
    const float* bias = (const float*)d_in[3];
    float* out = (float*)d_out;

    if (ws_size >= WT4_BYTES + KERNF_BYTES) {
        unsigned short* wt4 = (unsigned short*)d_ws;
        float* kernf = (float*)((char*)d_ws + WT4_BYTES);
        prepack<<<dim3(OO + BB), dim3(256), 0, stream>>>(w, kern, wt4, kernf);
        dwconv_mfma<<<dim3(5, 4, BB), dim3(256), 0, stream>>>(x, wt4, kernf, bias, out);
    } else {
        const int total = BB * OO * PP;
        dwconv_naive<<<dim3((total + 255) / 256), dim3(256), 0, stream>>>(
            x, kern, w, bias, out);
    }
}

// Round 4
// 381.952 us; speedup vs baseline: 6.2703x; 1.0199x over previous
//
#include <hip/hip_runtime.h>
#include <hip/hip_bf16.h>

typedef __attribute__((ext_vector_type(8))) short short8;
typedef __attribute__((ext_vector_type(4))) float floatx4;

#define BB 32
#define CC 256
#define OO 256
#define KS 7
#define HH 31
#define WW 31
#define HO 25
#define PP 625
#define SS 49

#define SLAB_PITCH 40        // ushort elems per row: 32 ci + 8 pad = 80 B
#define SLAB_ROWS  372       // 12 rows x 31 cols

// ws layout: Wt4 bf16 [49][8][256][32]  (6,422,528 B)  then kernf f32 [32][49][256]
#define WT4_ELEMS  ((size_t)SS * 8 * CC * 32)
#define WT4_BYTES  (WT4_ELEMS * 2)
#define KERNF_BYTES ((size_t)BB * SS * CC * 4)

static __device__ __forceinline__ unsigned pk2(float lo, float hi) {
    float2 f; f.x = lo; f.y = hi;
    __hip_bfloat162 h = __float22bfloat162_rn(f);   // v_cvt_pk_bf16_f32
    unsigned r;
    __builtin_memcpy(&r, &h, sizeof(r));
    return r;
}
static __device__ __forceinline__ float bflo(unsigned u) {
    return __builtin_bit_cast(float, u << 16);
}
static __device__ __forceinline__ float bfhi(unsigned u) {
    return __builtin_bit_cast(float, u & 0xffff0000u);
}

// modulated pack: 8 bf16 = bf16( wt[j] * kern[j] )
static __device__ __forceinline__ uint4 modpack(uint4 wv, float4 k0, float4 k1) {
    float p0 = bflo(wv.x) * k0.x, p1 = bfhi(wv.x) * k0.y;
    float p2 = bflo(wv.y) * k0.z, p3 = bfhi(wv.y) * k0.w;
    float p4 = bflo(wv.z) * k1.x, p5 = bfhi(wv.z) * k1.y;
    float p6 = bflo(wv.w) * k1.z, p7 = bfhi(wv.w) * k1.w;
    uint4 r;
    r.x = pk2(p0, p1); r.y = pk2(p2, p3); r.z = pk2(p4, p5); r.w = pk2(p6, p7);
    return r;
}

// ---------------------------------------------------------------------------
// Prepass: blocks 0..255 repack weight -> Wt4[s][cb][o][ci] bf16;
// blocks 256..287 reorder kern -> kernf[b][s][c] f32.
// ---------------------------------------------------------------------------
__global__ __launch_bounds__(256) void prepack(
        const float* __restrict__ w, const float* __restrict__ kern,
        unsigned short* __restrict__ wt4, float* __restrict__ kernf) {
    __shared__ float lbuf[CC * SS];   // 50176 B
    const int tid = threadIdx.x;
    const int bid = blockIdx.x;
    if (bid < OO) {
        const int o = bid;
        const float* src = w + (size_t)o * CC * SS;
        for (int i = tid; i < CC * SS; i += 256) lbuf[i] = src[i];
        __syncthreads();
        for (int it = 0; it < 7; ++it) {
            int idx = tid + it * 256;
            if (idx < SS * 32) {
                int coct = idx & 3, cbv = (idx >> 2) & 7, s = idx >> 5;
                int cbase = cbv * 32 + coct * 8;
                float v[8];
#pragma unroll
                for (int j = 0; j < 8; ++j) v[j] = lbuf[(cbase + j) * SS + s];
                uint4 pkt;
                pkt.x = pk2(v[0], v[1]); pkt.y = pk2(v[2], v[3]);
                pkt.z = pk2(v[4], v[5]); pkt.w = pk2(v[6], v[7]);
                *(uint4*)(wt4 + (((size_t)(s * 8 + cbv) * CC + o) * 32 + coct * 8)) = pkt;
            }
        }
    } else {
        const int b = bid - OO;
        const float* src = kern + (size_t)b * CC * SS;
        for (int i = tid; i < CC * SS; i += 256) lbuf[i] = src[i];
        __syncthreads();
        for (int it = 0; it < SS; ++it) {
            int idx = tid + it * 256;
            int s = idx >> 8, c = idx & 255;
            kernf[((size_t)b * SS + s) * CC + c] = lbuf[c * SS + s];
        }
    }
}

// ---------------------------------------------------------------------------
// Main: block = 64o x 128p of one batch, 4 waves of 32o x 64p.
// for cb (8 x 32c):   stage x slab  slabT[pos][ci] bf16 (29.8 KB)
//   for kk (7):       stage modulated A  amod[ll][oct][o][8] bf16 (28.7 KB)
//     for ll (7):     2 A ds_read_b128 + 4 B ds_read_b128 + 8 MFMA  (no global)
// ---------------------------------------------------------------------------
__global__ __launch_bounds__(256) void dwconv_mfma(
        const float* __restrict__ x,
        const unsigned short* __restrict__ wt4, const float* __restrict__ kernf,
        const float* __restrict__ bias, float* __restrict__ out) {
    __shared__ unsigned short slab[SLAB_ROWS * SLAB_PITCH];   // 29760 B
    __shared__ unsigned short amod[7 * 4 * 64 * 8];           // 28672 B

    const int tid = threadIdx.x;
    const int px = blockIdx.x, oy = blockIdx.y, b = blockIdx.z;
    const int p0 = px * 128, o0 = oy * 64;
    const int h0 = p0 / HO;
    const int rows = (HH - h0) < 12 ? (HH - h0) : 12;
    const int npos = rows * WW;

    const int lane = tid & 63, wid = tid >> 6;
    const int ow = wid & 1, pw = wid >> 1;        // o-sub(32), p-sub(64)
    const int lo16 = lane & 15, quad = lane >> 4;

    // B-fragment per-lane row offsets (ushort elems) for 4 p-subtiles of 16
    int bOffB[4];
#pragma unroll
    for (int pt = 0; pt < 4; ++pt) {
        int p = p0 + pw * 64 + pt * 16 + lo16;
        if (p > PP - 1) p = PP - 1;               // clamp; store guarded later
        int h = p / HO, ww_ = p - h * HO;
        int pos = (h - h0) * WW + ww_;
        bOffB[pt] = pos * SLAB_PITCH + quad * 8;
    }
    // A-fragment LDS offsets (elems): amod[ll][oct=quad][o][8]
    const int aBase0 = (quad * 64 + ow * 32 + lo16) * 8;
    const int aBase1 = aBase0 + 16 * 8;

    // staging roles: o_st = tid&63, oct_st = wave id
    const int o_st = tid & 63;
    const int oct_st = wid;

    floatx4 acc[2][4];
#pragma unroll
    for (int at = 0; at < 2; ++at)
#pragma unroll
        for (int pt = 0; pt < 4; ++pt)
            acc[at][pt] = (floatx4){0.f, 0.f, 0.f, 0.f};

    for (int cb = 0; cb < 8; ++cb) {
        __syncthreads();   // prior compute done: slab safe to overwrite
        // ---- stage slabT[pos][ci] ----
        {
            const int coct = wid;
            const int lpos = lane;
            const float* xsrc = x + ((size_t)(b * CC + cb * 32 + coct * 8)) * (HH * WW)
                                  + h0 * WW;
#pragma unroll
            for (int it = 0; it < 6; ++it) {
                int pos = lpos + it * 64;
                if (pos < npos) {
                    float v[8];
#pragma unroll
                    for (int j = 0; j < 8; ++j) v[j] = xsrc[j * (HH * WW) + pos];
                    uint4 pkt;
                    pkt.x = pk2(v[0], v[1]); pkt.y = pk2(v[2], v[3]);
                    pkt.z = pk2(v[4], v[5]); pkt.w = pk2(v[6], v[7]);
                    *(uint4*)(slab + pos * SLAB_PITCH + coct * 8) = pkt;
                }
            }
        }

        for (int kk = 0; kk < KS; ++kk) {
            __syncthreads();   // amod consumers of kk-1 done (and slab ready at kk=0)
            // ---- stage modulated A tile for shifts s = kk*7 .. kk*7+6 ----
            {
#pragma unroll
                for (int ll = 0; ll < KS; ++ll) {
                    const int s = kk * KS + ll;
                    uint4 wv = *(const uint4*)(wt4 +
                        (((size_t)(s * 8 + cb) * CC + o0 + o_st) * 32 + oct_st * 8));
                    const float* kf = kernf + ((size_t)b * SS + s) * CC + cb * 32 + oct_st * 8;
                    float4 kq0 = *(const float4*)(kf);
                    float4 kq1 = *(const float4*)(kf + 4);
                    uint4 m = modpack(wv, kq0, kq1);
                    *(uint4*)(amod + ((ll * 4 + oct_st) * 64 + o_st) * 8) = m;
                }
            }
            __syncthreads();   // amod ready
            const unsigned short* slabK = slab + kk * WW * SLAB_PITCH;
#pragma unroll
            for (int ll = 0; ll < KS; ++ll) {
                short8 sa0 = *(const short8*)(amod + ll * (4 * 64 * 8) + aBase0);
                short8 sa1 = *(const short8*)(amod + ll * (4 * 64 * 8) + aBase1);

                short8 sb0 = *(const short8*)(slabK + ll * SLAB_PITCH + bOffB[0]);
                short8 sb1 = *(const short8*)(slabK + ll * SLAB_PITCH + bOffB[1]);
                short8 sb2 = *(const short8*)(slabK + ll * SLAB_PITCH + bOffB[2]);
                short8 sb3 = *(const short8*)(slabK + ll * SLAB_PITCH + bOffB[3]);

                acc[0][0] = __builtin_amdgcn_mfma_f32_16x16x32_bf16(sa0, sb0, acc[0][0], 0, 0, 0);
                acc[0][1] = __builtin_amdgcn_mfma_f32_16x16x32_bf16(sa0, sb1, acc[0][1], 0, 0, 0);
                acc[0][2] = __builtin_amdgcn_mfma_f32_16x16x32_bf16(sa0, sb2, acc[0][2], 0, 0, 0);
                acc[0][3] = __builtin_amdgcn_mfma_f32_16x16x32_bf16(sa0, sb3, acc[0][3], 0, 0, 0);
                acc[1][0] = __builtin_amdgcn_mfma_f32_16x16x32_bf16(sa1, sb0, acc[1][0], 0, 0, 0);
                acc[1][1] = __builtin_amdgcn_mfma_f32_16x16x32_bf16(sa1, sb1, acc[1][1], 0, 0, 0);
                acc[1][2] = __builtin_amdgcn_mfma_f32_16x16x32_bf16(sa1, sb2, acc[1][2], 0, 0, 0);
                acc[1][3] = __builtin_amdgcn_mfma_f32_16x16x32_bf16(sa1, sb3, acc[1][3], 0, 0, 0);
            }
        }
    }

    // ---- epilogue: D col = p (lane&15), row = o (quad*4 + reg) ----
    const int pbase = p0 + pw * 64;
#pragma unroll
    for (int at = 0; at < 2; ++at) {
#pragma unroll
        for (int pt = 0; pt < 4; ++pt) {
            int p = pbase + pt * 16 + lo16;
            if (p < PP) {
#pragma unroll
                for (int r = 0; r < 4; ++r) {
                    int o = o0 + ow * 32 + at * 16 + quad * 4 + r;
                    out[((size_t)(b * OO + o)) * PP + p] = acc[at][pt][r] + bias[o];
                }
            }
        }
    }
}

// ---------------------------------------------------------------------------
// Fallback if ws too small: naive but correct.
// ---------------------------------------------------------------------------
__global__ __launch_bounds__(256) void dwconv_naive(
        const float* __restrict__ x, const float* __restrict__ kern,
        const float* __restrict__ w, const float* __restrict__ bias,
        float* __restrict__ out) {
    const int idx = blockIdx.x * 256 + threadIdx.x;
    if (idx >= BB * OO * PP) return;
    const int p = idx % PP;
    const int o = (idx / PP) % OO;
    const int b = idx / (PP * OO);
    const int h = p / HO;
    const int wq = p - h * HO;
    float acc = 0.f;
    for (int c = 0; c < CC; ++c) {
        const float* xp = x + ((size_t)(b * CC + c)) * (HH * WW) + h * WW + wq;
        const float* kp = kern + ((size_t)b * CC + c) * SS;
        const float* wp = w + ((size_t)o * CC + c) * SS;
#pragma unroll
        for (int s = 0; s < SS; ++s) {
            const int kk = s / KS;
            const int ll = s - kk * KS;
            acc += xp[kk * WW + ll] * kp[s] * wp[s];
        }
    }
    out[idx] = acc + bias[o];
}

extern "C" void kernel_launch(void* const* d_in, const int* in_sizes, int n_in,
                              void* d_out, int out_size, void* d_ws, size_t ws_size,
                              hipStream_t stream) {
    const float* x    = (const float*)d_in[0];
    const float* kern = (const float*)d_in[1];
    const float* w    = (const float*)d_in[2];
    const float* bias = (const float*)d_in[3];
    float* out = (float*)d_out;

    if (ws_size >= WT4_BYTES + KERNF_BYTES) {
        unsigned short* wt4 = (unsigned short*)d_ws;
        float* kernf = (float*)((char*)d_ws + WT4_BYTES);
        prepack<<<dim3(OO + BB), dim3(256), 0, stream>>>(w, kern, wt4, kernf);
        dwconv_mfma<<<dim3(5, 4, BB), dim3(256), 0, stream>>>(x, wt4, kernf, bias, out);
    } else {
        const int total = BB * OO * PP;
        dwconv_naive<<<dim3((total + 255) / 256), dim3(256), 0, stream>>>(
            x, kern, w, bias, out);
    }
}

// Round 5
// 337.732 us; speedup vs baseline: 7.0913x; 1.1309x over previous
//
#include <hip/hip_runtime.h>
#include <hip/hip_bf16.h>

typedef __attribute__((ext_vector_type(8))) short short8;
typedef __attribute__((ext_vector_type(4))) float floatx4;

#define BB 32
#define CC 256
#define OO 256
#define KS 7
#define HH 31
#define WW 31
#define HO 25
#define PP 625
#define SS 49

#define SLAB_PITCH 40        // ushort elems per pos row: 32 ci + 8 pad = 80 B
#define SLAB_ROWS  372       // 12 rows x 31 cols

// ws layout: wt4 bf16 [49][8][256][32] (6.4 MB) then kernf f32 [32][49][256]
#define WT4_ELEMS  ((size_t)SS * 8 * CC * 32)
#define WT4_BYTES  (WT4_ELEMS * 2)
#define KERNF_BYTES ((size_t)BB * SS * CC * 4)

static __device__ __forceinline__ unsigned pk2(float lo, float hi) {
    float2 f; f.x = lo; f.y = hi;
    __hip_bfloat162 h = __float22bfloat162_rn(f);   // v_cvt_pk_bf16_f32
    unsigned r;
    __builtin_memcpy(&r, &h, sizeof(r));
    return r;
}
static __device__ __forceinline__ float bflo(unsigned u) {
    return __builtin_bit_cast(float, u << 16);
}
static __device__ __forceinline__ float bfhi(unsigned u) {
    return __builtin_bit_cast(float, u & 0xffff0000u);
}

// modulated pack: 8 bf16 = bf16( wt[j] * kern[j] )
static __device__ __forceinline__ short8 modpack(uint4 wv, float4 k0, float4 k1) {
    float p0 = bflo(wv.x) * k0.x, p1 = bfhi(wv.x) * k0.y;
    float p2 = bflo(wv.y) * k0.z, p3 = bfhi(wv.y) * k0.w;
    float p4 = bflo(wv.z) * k1.x, p5 = bfhi(wv.z) * k1.y;
    float p6 = bflo(wv.w) * k1.z, p7 = bfhi(wv.w) * k1.w;
    uint4 r;
    r.x = pk2(p0, p1); r.y = pk2(p2, p3); r.z = pk2(p4, p5); r.w = pk2(p6, p7);
    return __builtin_bit_cast(short8, r);
}

// ---------------------------------------------------------------------------
// Prepass A: w[o][c][s] f32 -> wt4[s][cbv][o][ci] bf16. Grid 392 = 49 s x 8 cbv.
// No LDS: each thread gathers its o-row's 32 strided floats (L2-hot), packs,
// writes 64 contiguous bytes.
// ---------------------------------------------------------------------------
__global__ __launch_bounds__(256) void repack_w(const float* __restrict__ w,
                                                unsigned short* __restrict__ wt4) {
    const int bid = blockIdx.x;
    const int s = bid >> 3, cbv = bid & 7;
    const int o = threadIdx.x;
    const float* src = w + ((size_t)o * CC + cbv * 32) * SS + s;
    float v[32];
#pragma unroll
    for (int ci = 0; ci < 32; ++ci) v[ci] = src[(size_t)ci * SS];
    unsigned short* dst = wt4 + ((size_t)(s * 8 + cbv) * CC + o) * 32;
#pragma unroll
    for (int q = 0; q < 4; ++q) {
        uint4 pkt;
        pkt.x = pk2(v[q * 8 + 0], v[q * 8 + 1]);
        pkt.y = pk2(v[q * 8 + 2], v[q * 8 + 3]);
        pkt.z = pk2(v[q * 8 + 4], v[q * 8 + 5]);
        pkt.w = pk2(v[q * 8 + 6], v[q * 8 + 7]);
        *(uint4*)(dst + q * 8) = pkt;
    }
}

// ---------------------------------------------------------------------------
// Prepass B: kern[b][c][s] -> kernf[b][s][c] f32. Grid 224 = 32 b x 7 kk.
// ---------------------------------------------------------------------------
__global__ __launch_bounds__(256) void repack_k(const float* __restrict__ kern,
                                                float* __restrict__ kernf) {
    const int bid = blockIdx.x;
    const int b = bid / KS, kk = bid % KS;
    const int c = threadIdx.x;
    const float* src = kern + ((size_t)b * CC + c) * SS + kk * KS;
#pragma unroll
    for (int ll = 0; ll < KS; ++ll)
        kernf[((size_t)b * SS + kk * KS + ll) * CC + c] = src[ll];
}

// ---------------------------------------------------------------------------
// Main: block = 64o x 128p of one batch, 256 thr = 4 waves.
// Wave (pw, kw): pw = p-half (64p), kw = s-half (s 0..24 / 25..48).
// Each wave computes a full 64o x 64p tile over half of K (4A x 4B frags,
// 16 MFMA per s-step). B from LDS x-slab (staged once per cb, shared by all
// 4 waves); A direct from prepacked wt4 (global, L1/L2-hot via XCD swizzle),
// modulated by kernf in registers, prefetched one s ahead. Barriers: 2/cb.
// Epilogue: kw=1 partials through LDS (reusing slab), kw=0 adds bias+stores.
// ---------------------------------------------------------------------------
__global__ __launch_bounds__(256, 3) void dwconv_mfma(
        const float* __restrict__ x,
        const unsigned short* __restrict__ wt4, const float* __restrict__ kernf,
        const float* __restrict__ bias, float* __restrict__ out) {
    __shared__ unsigned short slab[SLAB_ROWS * SLAB_PITCH];   // 29760 B

    const int tid = threadIdx.x;
    const int id = blockIdx.x;
    const int oy = id & 3;              // XCD-pinned o-tile (id%8 -> 2 XCDs/oy)
    const int t  = id >> 2;
    const int px = t % 5, b = t / 5;
    const int p0 = px * 128, o0 = oy * 64;
    const int h0 = p0 / HO;
    const int rows = (HH - h0) < 12 ? (HH - h0) : 12;
    const int npos = rows * WW;

    const int lane = tid & 63, wid = tid >> 6;
    const int pw = wid & 1, kw = wid >> 1;
    const int lo16 = lane & 15, quad = lane >> 4;

    // B-fragment LDS offsets (ushort elems) for 4 p-subtiles of 16
    int bOff[4];
#pragma unroll
    for (int pt = 0; pt < 4; ++pt) {
        int p = p0 + pw * 64 + pt * 16 + lo16;
        if (p > PP - 1) p = PP - 1;     // clamp; store guarded later
        int h = p / HO, ww_ = p - h * HO;
        bOff[pt] = ((h - h0) * WW + ww_) * SLAB_PITCH + quad * 8;
    }

    const int s0 = kw ? 25 : 0;
    const int ns = kw ? 24 : 25;

    floatx4 acc[4][4];
#pragma unroll
    for (int at = 0; at < 4; ++at)
#pragma unroll
        for (int pt = 0; pt < 4; ++pt)
            acc[at][pt] = (floatx4){0.f, 0.f, 0.f, 0.f};

    for (int cb = 0; cb < 8; ++cb) {
        __syncthreads();   // prior compute done: slab safe to overwrite
        // ---- stage x slab: slabT[pos][ci] bf16, all 4 waves cooperate ----
        {
            const int coct = wid;       // 8-channel group
            const float* xsrc = x + ((size_t)(b * CC + cb * 32 + coct * 8)) * (HH * WW)
                                  + h0 * WW;
#pragma unroll
            for (int it = 0; it < 6; ++it) {
                int pos = lane + it * 64;
                if (pos < npos) {
                    float v[8];
#pragma unroll
                    for (int j = 0; j < 8; ++j) v[j] = xsrc[j * (HH * WW) + pos];
                    uint4 pkt;
                    pkt.x = pk2(v[0], v[1]); pkt.y = pk2(v[2], v[3]);
                    pkt.z = pk2(v[4], v[5]); pkt.w = pk2(v[6], v[7]);
                    *(uint4*)(slab + pos * SLAB_PITCH + coct * 8) = pkt;
                }
            }
        }
        __syncthreads();

        // ---- A/kern pointers at s = s0 for this cb ----
        const unsigned short* aptr0 = wt4 +
            (((size_t)s0 * 8 + cb) * CC + o0 + 0 * 16 + lo16) * 32 + quad * 8;
        const unsigned short* aptr2 = wt4 +
            (((size_t)s0 * 8 + cb) * CC + o0 + 2 * 16 + lo16) * 32 + quad * 8;
        const float* kptr = kernf + ((size_t)b * SS + s0) * CC + cb * 32 + quad * 8;

        uint4 wa[4];
        wa[0] = *(const uint4*)(aptr0);
        wa[1] = *(const uint4*)(aptr0 + 16 * 32);
        wa[2] = *(const uint4*)(aptr2);
        wa[3] = *(const uint4*)(aptr2 + 16 * 32);
        float4 kq0 = *(const float4*)(kptr);
        float4 kq1 = *(const float4*)(kptr + 4);

        for (int si = 0; si < ns; ++si) {
            const int s = s0 + si;
            // prefetch s+1 (wave-uniform branch)
            uint4 wn[4]; float4 kn0, kn1;
            if (si + 1 < ns) {
                aptr0 += (size_t)8 * CC * 32;
                aptr2 += (size_t)8 * CC * 32;
                kptr  += CC;
                wn[0] = *(const uint4*)(aptr0);
                wn[1] = *(const uint4*)(aptr0 + 16 * 32);
                wn[2] = *(const uint4*)(aptr2);
                wn[3] = *(const uint4*)(aptr2 + 16 * 32);
                kn0 = *(const float4*)(kptr);
                kn1 = *(const float4*)(kptr + 4);
            } else {
                wn[0] = wa[0]; wn[1] = wa[1]; wn[2] = wa[2]; wn[3] = wa[3];
                kn0 = kq0; kn1 = kq1;
            }

            const int kk = s / KS, ll = s - kk * KS;
            const unsigned short* slabS = slab + (kk * WW + ll) * SLAB_PITCH;

            short8 sb0 = *(const short8*)(slabS + bOff[0]);
            short8 sb1 = *(const short8*)(slabS + bOff[1]);
            short8 sb2 = *(const short8*)(slabS + bOff[2]);
            short8 sb3 = *(const short8*)(slabS + bOff[3]);

            short8 sa0 = modpack(wa[0], kq0, kq1);
            short8 sa1 = modpack(wa[1], kq0, kq1);
            short8 sa2 = modpack(wa[2], kq0, kq1);
            short8 sa3 = modpack(wa[3], kq0, kq1);

            acc[0][0] = __builtin_amdgcn_mfma_f32_16x16x32_bf16(sa0, sb0, acc[0][0], 0, 0, 0);
            acc[0][1] = __builtin_amdgcn_mfma_f32_16x16x32_bf16(sa0, sb1, acc[0][1], 0, 0, 0);
            acc[0][2] = __builtin_amdgcn_mfma_f32_16x16x32_bf16(sa0, sb2, acc[0][2], 0, 0, 0);
            acc[0][3] = __builtin_amdgcn_mfma_f32_16x16x32_bf16(sa0, sb3, acc[0][3], 0, 0, 0);
            acc[1][0] = __builtin_amdgcn_mfma_f32_16x16x32_bf16(sa1, sb0, acc[1][0], 0, 0, 0);
            acc[1][1] = __builtin_amdgcn_mfma_f32_16x16x32_bf16(sa1, sb1, acc[1][1], 0, 0, 0);
            acc[1][2] = __builtin_amdgcn_mfma_f32_16x16x32_bf16(sa1, sb2, acc[1][2], 0, 0, 0);
            acc[1][3] = __builtin_amdgcn_mfma_f32_16x16x32_bf16(sa1, sb3, acc[1][3], 0, 0, 0);
            acc[2][0] = __builtin_amdgcn_mfma_f32_16x16x32_bf16(sa2, sb0, acc[2][0], 0, 0, 0);
            acc[2][1] = __builtin_amdgcn_mfma_f32_16x16x32_bf16(sa2, sb1, acc[2][1], 0, 0, 0);
            acc[2][2] = __builtin_amdgcn_mfma_f32_16x16x32_bf16(sa2, sb2, acc[2][2], 0, 0, 0);
            acc[2][3] = __builtin_amdgcn_mfma_f32_16x16x32_bf16(sa2, sb3, acc[2][3], 0, 0, 0);
            acc[3][0] = __builtin_amdgcn_mfma_f32_16x16x32_bf16(sa3, sb0, acc[3][0], 0, 0, 0);
            acc[3][1] = __builtin_amdgcn_mfma_f32_16x16x32_bf16(sa3, sb1, acc[3][1], 0, 0, 0);
            acc[3][2] = __builtin_amdgcn_mfma_f32_16x16x32_bf16(sa3, sb2, acc[3][2], 0, 0, 0);
            acc[3][3] = __builtin_amdgcn_mfma_f32_16x16x32_bf16(sa3, sb3, acc[3][3], 0, 0, 0);

            wa[0] = wn[0]; wa[1] = wn[1]; wa[2] = wn[2]; wa[3] = wn[3];
            kq0 = kn0; kq1 = kn1;
        }
    }

    // ---- epilogue: combine kw halves via LDS (reuse slab), 2 rounds ----
    float* red = (float*)slab;   // [64 p][68 f32] = 17408 B <= 29760
    for (int round = 0; round < 2; ++round) {
        __syncthreads();
        if (kw == 1 && pw == round) {
#pragma unroll
            for (int at = 0; at < 4; ++at)
#pragma unroll
                for (int pt = 0; pt < 4; ++pt)
                    *(floatx4*)(red + (pt * 16 + lo16) * 68 + at * 16 + quad * 4)
                        = acc[at][pt];
        }
        __syncthreads();
        if (kw == 0 && pw == round) {
#pragma unroll
            for (int at = 0; at < 4; ++at) {
                const float4 bv = *(const float4*)(bias + o0 + at * 16 + quad * 4);
#pragma unroll
                for (int pt = 0; pt < 4; ++pt) {
                    floatx4 v = *(const floatx4*)(red + (pt * 16 + lo16) * 68
                                                  + at * 16 + quad * 4);
                    int p = p0 + round * 64 + pt * 16 + lo16;
                    if (p < PP) {
                        float r0 = acc[at][pt][0] + v[0] + bv.x;
                        float r1 = acc[at][pt][1] + v[1] + bv.y;
                        float r2 = acc[at][pt][2] + v[2] + bv.z;
                        float r3 = acc[at][pt][3] + v[3] + bv.w;
                        const int ob = o0 + at * 16 + quad * 4;
                        out[((size_t)(b * OO + ob + 0)) * PP + p] = r0;
                        out[((size_t)(b * OO + ob + 1)) * PP + p] = r1;
                        out[((size_t)(b * OO + ob + 2)) * PP + p] = r2;
                        out[((size_t)(b * OO + ob + 3)) * PP + p] = r3;
                    }
                }
            }
        }
    }
}

// ---------------------------------------------------------------------------
// Fallback if ws too small: naive but correct.
// ---------------------------------------------------------------------------
__global__ __launch_bounds__(256) void dwconv_naive(
        const float* __restrict__ x, const float* __restrict__ kern,
        const float* __restrict__ w, const float* __restrict__ bias,
        float* __restrict__ out) {
    const int idx = blockIdx.x * 256 + threadIdx.x;
    if (idx >= BB * OO * PP) return;
    const int p = idx % PP;
    const int o = (idx / PP) % OO;
    const int b = idx / (PP * OO);
    const int h = p / HO;
    const int wq = p - h * HO;
    float acc = 0.f;
    for (int c = 0; c < CC; ++c) {
        const float* xp = x + ((size_t)(b * CC + c)) * (HH * WW) + h * WW + wq;
        const float* kp = kern + ((size_t)b * CC + c) * SS;
        const float* wp = w + ((size_t)o * CC + c) * SS;
#pragma unroll
        for (int s = 0; s < SS; ++s) {
            const int kk = s / KS;
            const int ll = s - kk * KS;
            acc += xp[kk * WW + ll] * kp[s] * wp[s];
        }
    }
    out[idx] = acc + bias[o];
}

extern "C" void kernel_launch(void* const* d_in, const int* in_sizes, int n_in,
                              void* d_out, int out_size, void* d_ws, size_t ws_size,
                              hipStream_t stream) {
    const float* x    = (const float*)d_in[0];
    const float* kern = (const float*)d_in[1];
    const float* w    = (const float*)d_in[2];
    const float* bias = (const float*)d_in[3];
    float* out = (float*)d_out;

    if (ws_size >= WT4_BYTES + KERNF_BYTES) {
        unsigned short* wt4 = (unsigned short*)d_ws;
        float* kernf = (float*)((char*)d_ws + WT4_BYTES);
        repack_w<<<dim3(SS * 8), dim3(256), 0, stream>>>(w, wt4);
        repack_k<<<dim3(BB * KS), dim3(256), 0, stream>>>(kern, kernf);
        dwconv_mfma<<<dim3(640), dim3(256), 0, stream>>>(x, wt4, kernf, bias, out);
    } else {
        const int total = BB * OO * PP;
        dwconv_naive<<<dim3((total + 255) / 256), dim3(256), 0, stream>>>(
            x, kern, w, bias, out);
    }
}

// Round 7
// 307.780 us; speedup vs baseline: 7.7814x; 1.0973x over previous
//
#include <hip/hip_runtime.h>
#include <hip/hip_bf16.h>

typedef __attribute__((ext_vector_type(8)))  short short8;
typedef __attribute__((ext_vector_type(4)))  float floatx4;
typedef __attribute__((ext_vector_type(16))) float floatx16;

#define BB 32
#define CC 256
#define OO 256
#define KS 7
#define HH 31
#define WW 31
#define HO 25
#define PP 625
#define SS 49

#define SLAB_PITCH 40        // ushort elems per pos row: 32 ci + 8 pad = 80 B
// A 64-p tile spans ceil((p0+63)/25)-floor(p0/25)+7 <= 10 x-rows (px=1,3,5,7,8
// hit 10). R6 sized this 9 rows -> LDS overflow. 10 rows x 31 cols = 310.
#define SLAB_ROWS  310

// wt4 / wmod layout: [s][cb][kh][o][16ci]  (elems per (s,cb) = 2*256*16 = 8192)
#define WT4_ELEMS  ((size_t)SS * 8 * 2 * CC * 16)        // 3,211,264
#define WT4_BYTES  (WT4_ELEMS * 2)                       // 6,422,528
#define KERNF_BYTES ((size_t)BB * SS * CC * 4)           // 1,605,632
#define WMOD_ELEMS ((size_t)BB * WT4_ELEMS)
#define WMOD_BYTES (WMOD_ELEMS * 2)                      // 205,520,896

static __device__ __forceinline__ unsigned pk2(float lo, float hi) {
    float2 f; f.x = lo; f.y = hi;
    __hip_bfloat162 h = __float22bfloat162_rn(f);   // v_cvt_pk_bf16_f32
    unsigned r;
    __builtin_memcpy(&r, &h, sizeof(r));
    return r;
}
static __device__ __forceinline__ float bflo(unsigned u) {
    return __builtin_bit_cast(float, u << 16);
}
static __device__ __forceinline__ float bfhi(unsigned u) {
    return __builtin_bit_cast(float, u & 0xffff0000u);
}

// modulated pack: 8 bf16 = bf16( wt[j] * k[j] )
static __device__ __forceinline__ uint4 modpack(uint4 wv, float4 k0, float4 k1) {
    float p0 = bflo(wv.x) * k0.x, p1 = bfhi(wv.x) * k0.y;
    float p2 = bflo(wv.y) * k0.z, p3 = bfhi(wv.y) * k0.w;
    float p4 = bflo(wv.z) * k1.x, p5 = bfhi(wv.z) * k1.y;
    float p6 = bflo(wv.w) * k1.z, p7 = bfhi(wv.w) * k1.w;
    uint4 r;
    r.x = pk2(p0, p1); r.y = pk2(p2, p3); r.z = pk2(p4, p5); r.w = pk2(p6, p7);
    return r;
}

// ---------------------------------------------------------------------------
// Prepass A: w[o][c][s] f32 -> wt4[s][cb][kh][o][16] bf16. Grid 392 = (s*8+cb).
// ---------------------------------------------------------------------------
__global__ __launch_bounds__(256) void repack_w(const float* __restrict__ w,
                                                unsigned short* __restrict__ wt4) {
    const int bid = blockIdx.x;           // = s*8 + cb
    const int s = bid >> 3, cb = bid & 7;
    const int o = threadIdx.x;
    const float* src = w + ((size_t)o * CC + cb * 32) * SS + s;
    float v[32];
#pragma unroll
    for (int ci = 0; ci < 32; ++ci) v[ci] = src[(size_t)ci * SS];
#pragma unroll
    for (int kh = 0; kh < 2; ++kh) {
        unsigned short* dst = wt4 + ((size_t)bid * 2 + kh) * (CC * 16) + o * 16;
        uint4 p0, p1;
        p0.x = pk2(v[kh*16+0], v[kh*16+1]);  p0.y = pk2(v[kh*16+2], v[kh*16+3]);
        p0.z = pk2(v[kh*16+4], v[kh*16+5]);  p0.w = pk2(v[kh*16+6], v[kh*16+7]);
        p1.x = pk2(v[kh*16+8], v[kh*16+9]);  p1.y = pk2(v[kh*16+10], v[kh*16+11]);
        p1.z = pk2(v[kh*16+12], v[kh*16+13]); p1.w = pk2(v[kh*16+14], v[kh*16+15]);
        *(uint4*)(dst)     = p0;
        *(uint4*)(dst + 8) = p1;
    }
}

// ---------------------------------------------------------------------------
// Prepass B (fallback path only): kern[b][c][s] -> kernf[b][s][c] f32.
// ---------------------------------------------------------------------------
__global__ __launch_bounds__(256) void repack_k(const float* __restrict__ kern,
                                                float* __restrict__ kernf) {
    const int bid = blockIdx.x;
    const int b = bid / KS, kk = bid % KS;
    const int c = threadIdx.x;
    const float* src = kern + ((size_t)b * CC + c) * SS + kk * KS;
#pragma unroll
    for (int ll = 0; ll < KS; ++ll)
        kernf[((size_t)b * SS + kk * KS + ll) * CC + c] = src[ll];
}

// ---------------------------------------------------------------------------
// Premod: wmod[b][s][cb][kh][o][16] = wt4 * kern[b][c][s]. Grid 12544 = b*392+.
// kern reads are block-uniform (scalar loads); streaming writes 205 MB.
// ---------------------------------------------------------------------------
__global__ __launch_bounds__(256) void premod(
        const unsigned short* __restrict__ wt4, const float* __restrict__ kern,
        unsigned short* __restrict__ wmod) {
    const int bid = blockIdx.x;
    const int b = bid / 392, rc = bid % 392;
    const int s = rc >> 3, cb = rc & 7;
    const int o = threadIdx.x;
    const float* kp = kern + ((size_t)b * CC + cb * 32) * SS + s;
    float kf[32];
#pragma unroll
    for (int ci = 0; ci < 32; ++ci) kf[ci] = kp[(size_t)ci * SS];
#pragma unroll
    for (int kh = 0; kh < 2; ++kh) {
        const size_t off = ((size_t)rc * 2 + kh) * (CC * 16) + o * 16;
        uint4 w0 = *(const uint4*)(wt4 + off);
        uint4 w1 = *(const uint4*)(wt4 + off + 8);
        float4 k0a, k0b, k1a, k1b;
        k0a.x = kf[kh*16+0];  k0a.y = kf[kh*16+1];  k0a.z = kf[kh*16+2];  k0a.w = kf[kh*16+3];
        k0b.x = kf[kh*16+4];  k0b.y = kf[kh*16+5];  k0b.z = kf[kh*16+6];  k0b.w = kf[kh*16+7];
        k1a.x = kf[kh*16+8];  k1a.y = kf[kh*16+9];  k1a.z = kf[kh*16+10]; k1a.w = kf[kh*16+11];
        k1b.x = kf[kh*16+12]; k1b.y = kf[kh*16+13]; k1b.z = kf[kh*16+14]; k1b.w = kf[kh*16+15];
        uint4 m0 = modpack(w0, k0a, k0b);
        uint4 m1 = modpack(w1, k1a, k1b);
        unsigned short* dst = wmod + (size_t)b * WT4_ELEMS + off;
        *(uint4*)(dst)     = m0;
        *(uint4*)(dst + 8) = m1;
    }
}

// ---------------------------------------------------------------------------
// Main (big-ws path): block = 64o x 64p of one batch, 4 waves k-split (s
// quarters). Per s-step per wave: 4 global b128 A (premodulated, L2-hot),
// 4 ds b128 B, 8x mfma_32x32x16. Grid 1280 (= 4-5 blocks/CU), XCD-pinned so
// the 10 px blocks of one (b,oy) share the 1.6 MB wmod slice in their L2.
// ---------------------------------------------------------------------------
__global__ __launch_bounds__(256, 4) void dwconv_big(
        const float* __restrict__ x, const unsigned short* __restrict__ wmod,
        const float* __restrict__ bias, float* __restrict__ out) {
    __shared__ unsigned short slab[SLAB_ROWS * SLAB_PITCH];   // 24800 B

    const int tid = threadIdx.x;
    const int id = blockIdx.x;
    // id = hi*80 + px*8 + (g&7), g = hi*8 + (g&7) = b*4+oy  -> same-XCD groups
    const int hi = id / 80, rem = id % 80;
    const int px = rem >> 3;
    const int g = hi * 8 + (rem & 7);
    const int b = g >> 2, oy = g & 3;

    const int p0 = px * 64, o0 = oy * 64;
    const int h0 = p0 / HO;
    const int pmax = (p0 + 63 < PP - 1) ? p0 + 63 : PP - 1;
    const int rows = pmax / HO - h0 + 7;          // <= 10
    const int npos = rows * WW;

    const int lane = tid & 63, kw = tid >> 6;
    const int l32 = lane & 31, half = lane >> 5;  // half: k-oct within frag

    // B-fragment LDS offsets (ushort elems) for 2 p-subtiles of 32
    int bOff[2];
#pragma unroll
    for (int ph = 0; ph < 2; ++ph) {
        int p = p0 + ph * 32 + l32;
        if (p > PP - 1) p = PP - 1;               // clamp; store guarded later
        int h = p / HO, ww_ = p - h * HO;
        bOff[ph] = ((h - h0) * WW + ww_) * SLAB_PITCH + half * 8;
    }

    const int s0 = kw * 12 + (kw > 0 ? 1 : 0);    // 0,13,25,37
    const int ns = kw ? 12 : 13;

    const unsigned short* wmodb = wmod + (size_t)b * WT4_ELEMS
                                  + (size_t)(o0 + l32) * 16 + half * 8;

    floatx16 acc[2][2];
#pragma unroll
    for (int oh = 0; oh < 2; ++oh)
#pragma unroll
        for (int ph = 0; ph < 2; ++ph)
#pragma unroll
            for (int r = 0; r < 16; ++r) acc[oh][ph][r] = 0.f;

    for (int cb = 0; cb < 8; ++cb) {
        __syncthreads();   // prior compute done: slab safe to overwrite
        // ---- stage x slab: slabT[pos][ci] bf16, 4 waves x 8 channels ----
        {
            const float* xsrc = x + ((size_t)(b * CC + cb * 32 + kw * 8)) * (HH * WW)
                                  + h0 * WW;
#pragma unroll
            for (int it = 0; it < 5; ++it) {
                int pos = lane + it * 64;
                if (pos < npos) {
                    float v[8];
#pragma unroll
                    for (int j = 0; j < 8; ++j) v[j] = xsrc[j * (HH * WW) + pos];
                    uint4 pkt;
                    pkt.x = pk2(v[0], v[1]); pkt.y = pk2(v[2], v[3]);
                    pkt.z = pk2(v[4], v[5]); pkt.w = pk2(v[6], v[7]);
                    *(uint4*)(slab + pos * SLAB_PITCH + kw * 8) = pkt;
                }
            }
        }
        __syncthreads();

        // rolling A pointer: frag(oh,kh) = aptr + oh*512 + kh*4096; +65536/s
        const unsigned short* aptr = wmodb + (size_t)(s0 * 8 + cb) * 8192;

        uint4 wa0 = *(const uint4*)(aptr);
        uint4 wa1 = *(const uint4*)(aptr + 512);
        uint4 wa2 = *(const uint4*)(aptr + 4096);
        uint4 wa3 = *(const uint4*)(aptr + 4096 + 512);

        int s = s0, kk = s0 / KS, ll = s0 - (s0 / KS) * KS;
        for (int si = 0; si < ns; ++si) {
            // prefetch s+1
            uint4 wn0, wn1, wn2, wn3;
            if (si + 1 < ns) {
                aptr += 65536;
                wn0 = *(const uint4*)(aptr);
                wn1 = *(const uint4*)(aptr + 512);
                wn2 = *(const uint4*)(aptr + 4096);
                wn3 = *(const uint4*)(aptr + 4096 + 512);
            } else {
                wn0 = wa0; wn1 = wa1; wn2 = wa2; wn3 = wa3;
            }

            const unsigned short* slabS = slab + (kk * WW + ll) * SLAB_PITCH;
            short8 sb00 = *(const short8*)(slabS + bOff[0]);        // ph0 kh0
            short8 sb01 = *(const short8*)(slabS + bOff[0] + 16);   // ph0 kh1
            short8 sb10 = *(const short8*)(slabS + bOff[1]);        // ph1 kh0
            short8 sb11 = *(const short8*)(slabS + bOff[1] + 16);   // ph1 kh1

            short8 a00 = __builtin_bit_cast(short8, wa0);  // oh0 kh0
            short8 a10 = __builtin_bit_cast(short8, wa1);  // oh1 kh0
            short8 a01 = __builtin_bit_cast(short8, wa2);  // oh0 kh1
            short8 a11 = __builtin_bit_cast(short8, wa3);  // oh1 kh1

            acc[0][0] = __builtin_amdgcn_mfma_f32_32x32x16_bf16(a00, sb00, acc[0][0], 0, 0, 0);
            acc[0][1] = __builtin_amdgcn_mfma_f32_32x32x16_bf16(a00, sb10, acc[0][1], 0, 0, 0);
            acc[1][0] = __builtin_amdgcn_mfma_f32_32x32x16_bf16(a10, sb00, acc[1][0], 0, 0, 0);
            acc[1][1] = __builtin_amdgcn_mfma_f32_32x32x16_bf16(a10, sb10, acc[1][1], 0, 0, 0);
            acc[0][0] = __builtin_amdgcn_mfma_f32_32x32x16_bf16(a01, sb01, acc[0][0], 0, 0, 0);
            acc[0][1] = __builtin_amdgcn_mfma_f32_32x32x16_bf16(a01, sb11, acc[0][1], 0, 0, 0);
            acc[1][0] = __builtin_amdgcn_mfma_f32_32x32x16_bf16(a11, sb01, acc[1][0], 0, 0, 0);
            acc[1][1] = __builtin_amdgcn_mfma_f32_32x32x16_bf16(a11, sb11, acc[1][1], 0, 0, 0);

            wa0 = wn0; wa1 = wn1; wa2 = wn2; wa3 = wn3;
            ++s; if (++ll == KS) { ll = 0; ++kk; }
        }
    }

    // ---- epilogue: 4-way kw reduction via LDS (reuse slab as red[64p][68]) --
    float* red = (float*)slab;
    __syncthreads();
    if (kw == 3) {
#pragma unroll
        for (int oh = 0; oh < 2; ++oh)
#pragma unroll
            for (int ph = 0; ph < 2; ++ph)
#pragma unroll
                for (int c = 0; c < 4; ++c) {
                    floatx4 v4 = {acc[oh][ph][4*c+0], acc[oh][ph][4*c+1],
                                  acc[oh][ph][4*c+2], acc[oh][ph][4*c+3]};
                    *(floatx4*)(red + (ph * 32 + l32) * 68 + oh * 32 + c * 8 + 4 * half) = v4;
                }
    }
    __syncthreads();
    if (kw == 2) {
#pragma unroll
        for (int oh = 0; oh < 2; ++oh)
#pragma unroll
            for (int ph = 0; ph < 2; ++ph)
#pragma unroll
                for (int c = 0; c < 4; ++c) {
                    float* rp = red + (ph * 32 + l32) * 68 + oh * 32 + c * 8 + 4 * half;
                    floatx4 v4 = *(floatx4*)rp;
                    v4[0] += acc[oh][ph][4*c+0]; v4[1] += acc[oh][ph][4*c+1];
                    v4[2] += acc[oh][ph][4*c+2]; v4[3] += acc[oh][ph][4*c+3];
                    *(floatx4*)rp = v4;
                }
    }
    __syncthreads();
    if (kw == 1) {
#pragma unroll
        for (int oh = 0; oh < 2; ++oh)
#pragma unroll
            for (int ph = 0; ph < 2; ++ph)
#pragma unroll
                for (int c = 0; c < 4; ++c) {
                    float* rp = red + (ph * 32 + l32) * 68 + oh * 32 + c * 8 + 4 * half;
                    floatx4 v4 = *(floatx4*)rp;
                    v4[0] += acc[oh][ph][4*c+0]; v4[1] += acc[oh][ph][4*c+1];
                    v4[2] += acc[oh][ph][4*c+2]; v4[3] += acc[oh][ph][4*c+3];
                    *(floatx4*)rp = v4;
                }
    }
    __syncthreads();
    if (kw == 0) {
#pragma unroll
        for (int oh = 0; oh < 2; ++oh)
#pragma unroll
            for (int c = 0; c < 4; ++c) {
                const int ob = o0 + oh * 32 + c * 8 + 4 * half;
                const float4 bv = *(const float4*)(bias + ob);
#pragma unroll
                for (int ph = 0; ph < 2; ++ph) {
                    const int p = p0 + ph * 32 + l32;
                    floatx4 v4 = *(floatx4*)(red + (ph * 32 + l32) * 68 + oh * 32 + c * 8 + 4 * half);
                    if (p < PP) {
                        out[((size_t)(b * OO + ob + 0)) * PP + p] = v4[0] + acc[oh][ph][4*c+0] + bv.x;
                        out[((size_t)(b * OO + ob + 1)) * PP + p] = v4[1] + acc[oh][ph][4*c+1] + bv.y;
                        out[((size_t)(b * OO + ob + 2)) * PP + p] = v4[2] + acc[oh][ph][4*c+2] + bv.z;
                        out[((size_t)(b * OO + ob + 3)) * PP + p] = v4[3] + acc[oh][ph][4*c+3] + bv.w;
                    }
                }
            }
    }
}

// ---------------------------------------------------------------------------
// Fallback path (ws >= 8 MB): R5 kernel adapted to new wt4 layout. ~270 us.
// ---------------------------------------------------------------------------
#define SLAB2_ROWS 372
__global__ __launch_bounds__(256, 3) void dwconv_mid(
        const float* __restrict__ x,
        const unsigned short* __restrict__ wt4, const float* __restrict__ kernf,
        const float* __restrict__ bias, float* __restrict__ out) {
    __shared__ unsigned short slab[SLAB2_ROWS * SLAB_PITCH];   // 29760 B

    const int tid = threadIdx.x;
    const int id = blockIdx.x;
    const int oy = id & 3;
    const int t  = id >> 2;
    const int px = t % 5, b = t / 5;
    const int p0 = px * 128, o0 = oy * 64;
    const int h0 = p0 / HO;
    const int rows = (HH - h0) < 12 ? (HH - h0) : 12;
    const int npos = rows * WW;

    const int lane = tid & 63, wid = tid >> 6;
    const int pw = wid & 1, kw = wid >> 1;
    const int lo16 = lane & 15, quad = lane >> 4;

    int bOff[4];
#pragma unroll
    for (int pt = 0; pt < 4; ++pt) {
        int p = p0 + pw * 64 + pt * 16 + lo16;
        if (p > PP - 1) p = PP - 1;
        int h = p / HO, ww_ = p - h * HO;
        bOff[pt] = ((h - h0) * WW + ww_) * SLAB_PITCH + quad * 8;
    }

    const int s0 = kw ? 25 : 0;
    const int ns = kw ? 24 : 25;

    floatx4 acc[4][4];
#pragma unroll
    for (int at = 0; at < 4; ++at)
#pragma unroll
        for (int pt = 0; pt < 4; ++pt)
            acc[at][pt] = (floatx4){0.f, 0.f, 0.f, 0.f};

    for (int cb = 0; cb < 8; ++cb) {
        __syncthreads();
        {
            const int coct = wid;
            const float* xsrc = x + ((size_t)(b * CC + cb * 32 + coct * 8)) * (HH * WW)
                                  + h0 * WW;
#pragma unroll
            for (int it = 0; it < 6; ++it) {
                int pos = lane + it * 64;
                if (pos < npos) {
                    float v[8];
#pragma unroll
                    for (int j = 0; j < 8; ++j) v[j] = xsrc[j * (HH * WW) + pos];
                    uint4 pkt;
                    pkt.x = pk2(v[0], v[1]); pkt.y = pk2(v[2], v[3]);
                    pkt.z = pk2(v[4], v[5]); pkt.w = pk2(v[6], v[7]);
                    *(uint4*)(slab + pos * SLAB_PITCH + coct * 8) = pkt;
                }
            }
        }
        __syncthreads();

        const unsigned short* aptrA = wt4 +
            ((size_t)(s0 * 8 + cb) * 2 + (quad >> 1)) * 4096 +
            (size_t)(o0 + lo16) * 16 + (quad & 1) * 8;
        const float* kptr = kernf + ((size_t)b * SS + s0) * CC + cb * 32 + quad * 8;

        uint4 wa[4];
        wa[0] = *(const uint4*)(aptrA);
        wa[1] = *(const uint4*)(aptrA + 256);
        wa[2] = *(const uint4*)(aptrA + 512);
        wa[3] = *(const uint4*)(aptrA + 768);
        float4 kq0 = *(const float4*)(kptr);
        float4 kq1 = *(const float4*)(kptr + 4);

        for (int si = 0; si < ns; ++si) {
            const int s = s0 + si;
            uint4 wn[4]; float4 kn0, kn1;
            if (si + 1 < ns) {
                aptrA += 65536;
                kptr  += CC;
                wn[0] = *(const uint4*)(aptrA);
                wn[1] = *(const uint4*)(aptrA + 256);
                wn[2] = *(const uint4*)(aptrA + 512);
                wn[3] = *(const uint4*)(aptrA + 768);
                kn0 = *(const float4*)(kptr);
                kn1 = *(const float4*)(kptr + 4);
            } else {
                wn[0] = wa[0]; wn[1] = wa[1]; wn[2] = wa[2]; wn[3] = wa[3];
                kn0 = kq0; kn1 = kq1;
            }

            const int kk = s / KS, ll = s - kk * KS;
            const unsigned short* slabS = slab + (kk * WW + ll) * SLAB_PITCH;

            short8 sb0 = *(const short8*)(slabS + bOff[0]);
            short8 sb1 = *(const short8*)(slabS + bOff[1]);
            short8 sb2 = *(const short8*)(slabS + bOff[2]);
            short8 sb3 = *(const short8*)(slabS + bOff[3]);

            short8 sa0 = __builtin_bit_cast(short8, modpack(wa[0], kq0, kq1));
            short8 sa1 = __builtin_bit_cast(short8, modpack(wa[1], kq0, kq1));
            short8 sa2 = __builtin_bit_cast(short8, modpack(wa[2], kq0, kq1));
            short8 sa3 = __builtin_bit_cast(short8, modpack(wa[3], kq0, kq1));

            acc[0][0] = __builtin_amdgcn_mfma_f32_16x16x32_bf16(sa0, sb0, acc[0][0], 0, 0, 0);
            acc[0][1] = __builtin_amdgcn_mfma_f32_16x16x32_bf16(sa0, sb1, acc[0][1], 0, 0, 0);
            acc[0][2] = __builtin_amdgcn_mfma_f32_16x16x32_bf16(sa0, sb2, acc[0][2], 0, 0, 0);
            acc[0][3] = __builtin_amdgcn_mfma_f32_16x16x32_bf16(sa0, sb3, acc[0][3], 0, 0, 0);
            acc[1][0] = __builtin_amdgcn_mfma_f32_16x16x32_bf16(sa1, sb0, acc[1][0], 0, 0, 0);
            acc[1][1] = __builtin_amdgcn_mfma_f32_16x16x32_bf16(sa1, sb1, acc[1][1], 0, 0, 0);
            acc[1][2] = __builtin_amdgcn_mfma_f32_16x16x32_bf16(sa1, sb2, acc[1][2], 0, 0, 0);
            acc[1][3] = __builtin_amdgcn_mfma_f32_16x16x32_bf16(sa1, sb3, acc[1][3], 0, 0, 0);
            acc[2][0] = __builtin_amdgcn_mfma_f32_16x16x32_bf16(sa2, sb0, acc[2][0], 0, 0, 0);
            acc[2][1] = __builtin_amdgcn_mfma_f32_16x16x32_bf16(sa2, sb1, acc[2][1], 0, 0, 0);
            acc[2][2] = __builtin_amdgcn_mfma_f32_16x16x32_bf16(sa2, sb2, acc[2][2], 0, 0, 0);
            acc[2][3] = __builtin_amdgcn_mfma_f32_16x16x32_bf16(sa2, sb3, acc[2][3], 0, 0, 0);
            acc[3][0] = __builtin_amdgcn_mfma_f32_16x16x32_bf16(sa3, sb0, acc[3][0], 0, 0, 0);
            acc[3][1] = __builtin_amdgcn_mfma_f32_16x16x32_bf16(sa3, sb1, acc[3][1], 0, 0, 0);
            acc[3][2] = __builtin_amdgcn_mfma_f32_16x16x32_bf16(sa3, sb2, acc[3][2], 0, 0, 0);
            acc[3][3] = __builtin_amdgcn_mfma_f32_16x16x32_bf16(sa3, sb3, acc[3][3], 0, 0, 0);

            wa[0] = wn[0]; wa[1] = wn[1]; wa[2] = wn[2]; wa[3] = wn[3];
            kq0 = kn0; kq1 = kn1;
        }
    }

    float* red = (float*)slab;
    for (int round = 0; round < 2; ++round) {
        __syncthreads();
        if (kw == 1 && pw == round) {
#pragma unroll
            for (int at = 0; at < 4; ++at)
#pragma unroll
                for (int pt = 0; pt < 4; ++pt)
                    *(floatx4*)(red + (pt * 16 + lo16) * 68 + at * 16 + quad * 4)
                        = acc[at][pt];
        }
        __syncthreads();
        if (kw == 0 && pw == round) {
#pragma unroll
            for (int at = 0; at < 4; ++at) {
                const float4 bv = *(const float4*)(bias + o0 + at * 16 + quad * 4);
#pragma unroll
                for (int pt = 0; pt < 4; ++pt) {
                    floatx4 v = *(const floatx4*)(red + (pt * 16 + lo16) * 68
                                                  + at * 16 + quad * 4);
                    int p = p0 + round * 64 + pt * 16 + lo16;
                    if (p < PP) {
                        const int ob = o0 + at * 16 + quad * 4;
                        out[((size_t)(b * OO + ob + 0)) * PP + p] = acc[at][pt][0] + v[0] + bv.x;
                        out[((size_t)(b * OO + ob + 1)) * PP + p] = acc[at][pt][1] + v[1] + bv.y;
                        out[((size_t)(b * OO + ob + 2)) * PP + p] = acc[at][pt][2] + v[2] + bv.z;
                        out[((size_t)(b * OO + ob + 3)) * PP + p] = acc[at][pt][3] + v[3] + bv.w;
                    }
                }
            }
        }
    }
}

// ---------------------------------------------------------------------------
// Last-resort fallback: naive but correct.
// ---------------------------------------------------------------------------
__global__ __launch_bounds__(256) void dwconv_naive(
        const float* __restrict__ x, const float* __restrict__ kern,
        const float* __restrict__ w, const float* __restrict__ bias,
        float* __restrict__ out) {
    const int idx = blockIdx.x * 256 + threadIdx.x;
    if (idx >= BB * OO * PP) return;
    const int p = idx % PP;
    const int o = (idx / PP) % OO;
    const int b = idx / (PP * OO);
    const int h = p / HO;
    const int wq = p - h * HO;
    float acc = 0.f;
    for (int c = 0; c < CC; ++c) {
        const float* xp = x + ((size_t)(b * CC + c)) * (HH * WW) + h * WW + wq;
        const float* kp = kern + ((size_t)b * CC + c) * SS;
        const float* wp = w + ((size_t)o * CC + c) * SS;
#pragma unroll
        for (int s = 0; s < SS; ++s) {
            const int kk = s / KS;
            const int ll = s - kk * KS;
            acc += xp[kk * WW + ll] * kp[s] * wp[s];
        }
    }
    out[idx] = acc + bias[o];
}

extern "C" void kernel_launch(void* const* d_in, const int* in_sizes, int n_in,
                              void* d_out, int out_size, void* d_ws, size_t ws_size,
                              hipStream_t stream) {
    const float* x    = (const float*)d_in[0];
    const float* kern = (const float*)d_in[1];
    const float* w    = (const float*)d_in[2];
    const float* bias = (const float*)d_in[3];
    float* out = (float*)d_out;

    if (ws_size >= WT4_BYTES + WMOD_BYTES) {
        unsigned short* wt4  = (unsigned short*)d_ws;
        unsigned short* wmod = (unsigned short*)((char*)d_ws + WT4_BYTES);
        repack_w<<<dim3(SS * 8), dim3(256), 0, stream>>>(w, wt4);
        premod<<<dim3(BB * SS * 8), dim3(256), 0, stream>>>(wt4, kern, wmod);
        dwconv_big<<<dim3(1280), dim3(256), 0, stream>>>(x, wmod, bias, out);
    } else if (ws_size >= WT4_BYTES + KERNF_BYTES) {
        unsigned short* wt4 = (unsigned short*)d_ws;
        float* kernf = (float*)((char*)d_ws + WT4_BYTES);
        repack_w<<<dim3(SS * 8), dim3(256), 0, stream>>>(w, wt4);
        repack_k<<<dim3(BB * KS), dim3(256), 0, stream>>>(kern, kernf);
        dwconv_mid<<<dim3(640), dim3(256), 0, stream>>>(x, wt4, kernf, bias, out);
    } else {
        const int total = BB * OO * PP;
        dwconv_naive<<<dim3((total + 255) / 256), dim3(256), 0, stream>>>(
            x, kern, w, bias, out);
    }
}